// Round 4
// baseline (401.166 us; speedup 1.0000x reference)
//
#include <hip/hip_runtime.h>
#include <stdint.h>

typedef float  floatx4 __attribute__((ext_vector_type(4)));
typedef short  shortx8 __attribute__((ext_vector_type(8)));  // 8 bf16 = 4 VGPRs

// ---------------------------------------------------------------------------
// helpers
// ---------------------------------------------------------------------------
// f32 -> bf16 bits, exact truncation (only used on e4m3-grid values, <=4
// mantissa bits -> lossless).
__device__ __forceinline__ uint16_t f2b_exact(float f) {
  return (uint16_t)(__float_as_uint(f) >> 16);
}

// Round v (pre-clamped to [-448,448]) to the e4m3fn grid, RNE. Exact:
// v*rstep is exact (rstep = 2^k), rintf is RNE, *step is exact.
__device__ __forceinline__ float quant_e4m3_value(float v) {
  float av = fabsf(v);
  float step, rstep;
  if (av < 0.015625f) {            // below 2^-6: e4m3 subnormal region
    step  = 0.001953125f;          // 2^-9
    rstep = 512.0f;
  } else {
    uint32_t e = __float_as_uint(av) >> 23;            // biased exponent
    step  = __uint_as_float((e - 3u) << 23);           // 2^(E-3)
    rstep = __uint_as_float((257u - e) << 23);         // 2^(3-E)
  }
  return rintf(v * rstep) * step;
}

// Decode e4m3fn byte -> f32 (exact; clipped qweight has no NaN).
__device__ __forceinline__ float dec_e4m3(uint32_t b) {
  uint32_t s = (b & 0x80u) << 24;
  uint32_t e = (b >> 3) & 15u, m = b & 7u;
  float mag;
  if (e == 0u) mag = (float)m * 0.001953125f;                         // m*2^-9
  else         mag = __uint_as_float(((e + 120u) << 23) | (m << 20)); // (1+m/8)*2^(e-7)
  return __uint_as_float(s | __float_as_uint(mag));
}

// ---------------------------------------------------------------------------
// Kernel 0: detect qweight storage format. One wave, graph-safe (pure
// function of input, recomputed every call).
//   mode 2: f32 holding e4m3 values  -> every uint32 has bits[19:0]==0
//   mode 1: bf16 holding e4m3 values -> every uint16 has bits[3:0]==0
//   mode 0: raw fp8 bytes            -> neither
// ---------------------------------------------------------------------------
__global__ void detect_mode_kernel(const uint32_t* __restrict__ qw,
                                   int* __restrict__ mode) {
  int t = threadIdx.x;  // 64 threads
  uint32_t w0 = qw[t], w1 = qw[t + 64];
  bool a = ((w0 & 0xFFFFFu) == 0u) && ((w1 & 0xFFFFFu) == 0u);
  uint32_t nib = (w0 | (w0 >> 16) | w1 | (w1 >> 16)) & 0xFu;
  bool b = (nib == 0u);
  unsigned long long ba = __ballot(a);
  unsigned long long bb = __ballot(b);
  if (t == 0) mode[0] = (ba == ~0ull) ? 2 : ((bb == ~0ull) ? 1 : 0);
}

// ---------------------------------------------------------------------------
// Kernel 1: quantize x (f32): clip(x/s, +-448) -> e4m3-grid value -> bf16.
// float4 in (16B), ushort4 out (8B) per thread.
// ---------------------------------------------------------------------------
__global__ __launch_bounds__(256) void quantize_x_kernel(
    const float4* __restrict__ x, const float* __restrict__ s_ptr,
    ushort4* __restrict__ q, int n4) {
  int i = blockIdx.x * 256 + threadIdx.x;
  if (i >= n4) return;
  const float s = s_ptr[0];
  float4 v = x[i];
  // IEEE division to match reference x / input_scale
  float a0 = quant_e4m3_value(fminf(fmaxf(v.x / s, -448.0f), 448.0f));
  float a1 = quant_e4m3_value(fminf(fmaxf(v.y / s, -448.0f), 448.0f));
  float a2 = quant_e4m3_value(fminf(fmaxf(v.z / s, -448.0f), 448.0f));
  float a3 = quant_e4m3_value(fminf(fmaxf(v.w / s, -448.0f), 448.0f));
  ushort4 o;
  o.x = f2b_exact(a0);
  o.y = f2b_exact(a1);
  o.z = f2b_exact(a2);
  o.w = f2b_exact(a3);
  q[i] = o;
}

// ---------------------------------------------------------------------------
// Kernel 2: weights -> e4m3 values as bf16 [N][K], per detected mode.
// Branch is wave-uniform (mode is a device-memory scalar).
// ---------------------------------------------------------------------------
__global__ __launch_bounds__(256) void prep_w_kernel(
    const uint8_t* __restrict__ qw, const int* __restrict__ mode,
    ushort4* __restrict__ w16, int n4) {
  int i = blockIdx.x * 256 + threadIdx.x;
  if (i >= n4) return;
  int m = mode[0];
  ushort4 o;
  if (m == 1) {                       // bf16 storage: straight copy
    o = ((const ushort4*)qw)[i];
  } else if (m == 2) {                // f32 storage: exact truncate to bf16
    float4 v = ((const float4*)qw)[i];
    o.x = f2b_exact(v.x);
    o.y = f2b_exact(v.y);
    o.z = f2b_exact(v.z);
    o.w = f2b_exact(v.w);
  } else {                            // raw fp8 bytes: decode
    uint32_t p = ((const uint32_t*)qw)[i];
    o.x = f2b_exact(dec_e4m3(p & 0xffu));
    o.y = f2b_exact(dec_e4m3((p >> 8) & 0xffu));
    o.z = f2b_exact(dec_e4m3((p >> 16) & 0xffu));
    o.w = f2b_exact(dec_e4m3(p >> 24));
  }
  w16[i] = o;
}

// ---------------------------------------------------------------------------
// Kernel 3: bf16 GEMM  C[m,n] = sc * sum_k A[m,k]*B[n,k] + bias[n], f32 out.
// 128x128 tile, BK=64, 256 thr / 4 waves, wave = 64x64 via 4x4 grid of
// mfma_f32_16x16x32_bf16 (HW-verified layouts m89/m91/m120).
// LDS row stride 144 B (128 data + 16 pad): 2-way bank aliasing only (free).
// ---------------------------------------------------------------------------
#define LDS_STRIDE 144

__global__ __launch_bounds__(256) void gemm_bf16_kernel(
    const uint8_t* __restrict__ A, const uint8_t* __restrict__ B,
    const float* __restrict__ wscale, const float* __restrict__ iscale,
    const float* __restrict__ bias, float* __restrict__ out,
    int M, int N, int K) {
  __shared__ uint8_t lsA[128 * LDS_STRIDE];  // 18 KB
  __shared__ uint8_t lsB[128 * LDS_STRIDE];  // 18 KB

  const int tid  = threadIdx.x;
  const int wave = tid >> 6;
  const int lane = tid & 63;
  const int bm = blockIdx.y;
  const int bn = blockIdx.x;

  const int wm = (wave & 1) * 64;
  const int wn = (wave >> 1) * 64;

  // staging: thread t handles 16B chunk (t&7) of rows (t>>3) + 32*it
  const int srow   = tid >> 3;         // 0..31
  const int schunk = (tid & 7) * 16;   // byte offset within 128B row-slice

  const size_t Kb = (size_t)K * 2;
  const uint8_t* gA = A + (size_t)(bm * 128 + srow) * Kb + schunk;
  const uint8_t* gB = B + (size_t)(bn * 128 + srow) * Kb + schunk;
  uint8_t* lA = &lsA[srow * LDS_STRIDE + schunk];
  uint8_t* lB = &lsB[srow * LDS_STRIDE + schunk];

  const int r15  = lane & 15;
  const int quad = lane >> 4;

  floatx4 acc[4][4];
#pragma unroll
  for (int i = 0; i < 4; ++i)
#pragma unroll
    for (int j = 0; j < 4; ++j) acc[i][j] = (floatx4){0.f, 0.f, 0.f, 0.f};

  for (int k0 = 0; k0 < K; k0 += 64) {
    __syncthreads();  // previous iteration's LDS reads done
    const size_t gk = (size_t)k0 * 2;
#pragma unroll
    for (int it = 0; it < 4; ++it) {
      *(uint4*)(lA + it * (32 * LDS_STRIDE)) =
          *(const uint4*)(gA + gk + it * (32 * Kb));
      *(uint4*)(lB + it * (32 * LDS_STRIDE)) =
          *(const uint4*)(gB + gk + it * (32 * Kb));
    }
    __syncthreads();  // staging visible to all waves

#pragma unroll
    for (int kk = 0; kk < 2; ++kk) {
      const int off = kk * 64 + quad * 16;  // k = kk*32 + quad*8 (bytes)
      shortx8 af[4], bf[4];
#pragma unroll
      for (int mi = 0; mi < 4; ++mi)
        af[mi] = *(const shortx8*)(&lsA[(wm + mi * 16 + r15) * LDS_STRIDE + off]);
#pragma unroll
      for (int ni = 0; ni < 4; ++ni)
        bf[ni] = *(const shortx8*)(&lsB[(wn + ni * 16 + r15) * LDS_STRIDE + off]);
#pragma unroll
      for (int mi = 0; mi < 4; ++mi)
#pragma unroll
        for (int ni = 0; ni < 4; ++ni)
          acc[mi][ni] = __builtin_amdgcn_mfma_f32_16x16x32_bf16(
              af[mi], bf[ni], acc[mi][ni], 0, 0, 0);
    }
  }

  // epilogue: C/D layout col=lane&15 (n), row=quad*4+reg (m)  [m89/m91]
  const float sc = wscale[0] * iscale[0];
  const int rq = quad * 4;
#pragma unroll
  for (int ni = 0; ni < 4; ++ni) {
    const int col = bn * 128 + wn + ni * 16 + r15;
    const float bv = bias[col];
#pragma unroll
    for (int mi = 0; mi < 4; ++mi) {
      const int row = bm * 128 + wm + mi * 16 + rq;
      float* o = out + (size_t)row * N + col;
#pragma unroll
      for (int r = 0; r < 4; ++r)
        o[(size_t)r * N] = acc[mi][ni][r] * sc + bv;
    }
  }
}

// ---------------------------------------------------------------------------
extern "C" void kernel_launch(void* const* d_in, const int* in_sizes, int n_in,
                              void* d_out, int out_size, void* d_ws,
                              size_t ws_size, hipStream_t stream) {
  // Storage (deduced R0-R3): x f32, qweight bf16 (e4m3 values, runtime
  // double-checked), wscale/iscale/bias f32, out f32.
  const float*   x      = (const float*)d_in[0];   // f32 [M,K]
  const uint8_t* qw     = (const uint8_t*)d_in[1]; // bf16 (detected) [N,K]
  const float*   wscale = (const float*)d_in[2];   // f32 scalar
  const float*   iscale = (const float*)d_in[3];   // f32 scalar
  const float*   bias   = (const float*)d_in[4];   // f32 [N]
  float*         out    = (float*)d_out;

  const int N = in_sizes[4];          // 2048
  const int K = in_sizes[1] / N;      // 2048
  const int M = in_sizes[0] / K;      // 16384

  // ws layout: [0, M*K*2) qx bf16 ; [+, N*K*2) w16 bf16 ; [+, 4) mode flag
  uint8_t* qx   = (uint8_t*)d_ws;
  uint8_t* w16  = qx + (size_t)M * K * 2;
  int*     mode = (int*)(w16 + (size_t)N * K * 2);

  detect_mode_kernel<<<1, 64, 0, stream>>>((const uint32_t*)qw, mode);

  const int nx4 = in_sizes[0] / 4;
  quantize_x_kernel<<<(nx4 + 255) / 256, 256, 0, stream>>>(
      (const float4*)x, iscale, (ushort4*)qx, nx4);

  const int nw4 = in_sizes[1] / 4;
  prep_w_kernel<<<(nw4 + 255) / 256, 256, 0, stream>>>(
      qw, mode, (ushort4*)w16, nw4);

  dim3 grid(N / 128, M / 128);
  gemm_bf16_kernel<<<grid, 256, 0, stream>>>(qx, w16, wscale, iscale, bias,
                                             out, M, N, K);
}